// Round 5
// baseline (469.470 us; speedup 1.0000x reference)
//
#include <hip/hip_runtime.h>
#include <hip/hip_fp16.h>

// LinkPredictorBackbone: GCN backbone, N=100000 nodes, E=1600000 edges, C=128.
// Round 5 pipeline:
//   graph build: bucket-count (LDS hist) -> bucket scan -> bin (bucket-major)
//                -> fill_bucket (per-node count/rowptr/dinv/col all in-LDS)
//   weights: pack all 5 128x128 fp32 W into bf16 hi/lo MFMA B-fragment records
//   gemm_mfma<AFP16>: split-bf16 MFMA; A fp32 (layer 0) or fp16 (h);
//     mode 0 -> h fp16 row-major; mode 1 -> hwc fp16 chunk-major [8][N][16];
//     mode 2 -> fp32 d_out
//   agg_bn_relu_c: 8 chunks of 16ch PINNED to XCDs via chunk = blockIdx&7
//     (per-XCD gather slice 3.2MB -> L2-resident); 8-lane group per node.

#define HIDC 128
#define BN_EPS 1e-5f
#define DPB 256          // dsts per bucket
#define NBK 512          // bucket array size (>= ceil(N/DPB))
#define BIN_CHUNK 8192   // edges per binning block

typedef short bf16x8 __attribute__((ext_vector_type(8)));
typedef float f32x4 __attribute__((ext_vector_type(4)));

__device__ __forceinline__ unsigned short f2bf_rn(float x) {
    unsigned int u = __float_as_uint(x);
    unsigned int r = u + 0x7fffu + ((u >> 16) & 1u);
    return (unsigned short)(r >> 16);
}
__device__ __forceinline__ float bf2f(unsigned short b) {
    return __uint_as_float(((unsigned int)b) << 16);
}

// ---------------- graph build ----------------

__global__ void detect64(const unsigned int* ei, int* flag) {
    if (threadIdx.x != 0 || blockIdx.x != 0) return;
    int is64 = 1;
    for (int i = 0; i < 64; ++i) {
        if (ei[2 * i + 1] != 0u) { is64 = 0; break; }
    }
    *flag = is64;
}

__global__ __launch_bounds__(256) void bucket_count(const void* __restrict__ ei,
                                                    const int* __restrict__ flag,
                                                    int* __restrict__ bkt, int e) {
    __shared__ int h[NBK];
    int t = threadIdx.x;
    for (int i = t; i < NBK; i += 256) h[i] = 0;
    __syncthreads();
    int base = blockIdx.x * BIN_CHUNK;
    int cnt = e - base;
    if (cnt > BIN_CHUNK) cnt = BIN_CHUNK;
    if (*flag) {
        const long long* pd = (const long long*)ei + e;
        for (int i = t; i < cnt; i += 256) atomicAdd(&h[((int)pd[base + i]) >> 8], 1);
    } else {
        const int* pd = (const int*)ei + e;
        for (int i = t; i < cnt; i += 256) atomicAdd(&h[pd[base + i] >> 8], 1);
    }
    __syncthreads();
    for (int i = t; i < NBK; i += 256) if (h[i]) atomicAdd(&bkt[i], h[i]);
}

// single block of 512: exclusive scan of bucket counts -> bbase (cursor copy bc)
__global__ void scan_buckets(const int* __restrict__ bkt, int* __restrict__ bbase,
                             int* __restrict__ bc, int* __restrict__ rowptr,
                             int n, int e, int nbk) {
    __shared__ int s[NBK];
    int t = threadIdx.x;
    int v = (t < nbk) ? bkt[t] : 0;
    s[t] = v;
    __syncthreads();
    for (int off = 1; off < NBK; off <<= 1) {
        int val = (t >= off) ? s[t - off] : 0;
        __syncthreads();
        s[t] += val;
        __syncthreads();
    }
    int excl = s[t] - v;     // exclusive prefix (== e for t >= nbk)
    bbase[t] = excl;
    bc[t] = excl;
    if (t == 0) rowptr[n] = e;
}

// bin edges into bucket-major order with coalesced flushes via LDS staging
__global__ __launch_bounds__(256) void bin_pairs(const void* __restrict__ ei,
                                                 const int* __restrict__ flag,
                                                 int* __restrict__ bc,
                                                 int2* __restrict__ staged, int e) {
    __shared__ int hist[NBK];      // later reused as local placement cursor
    __shared__ int lstart[NBK];
    __shared__ int gbase[NBK];
    __shared__ int sdata[256];
    __shared__ int2 stage[BIN_CHUNK];   // 64 KB

    int t = threadIdx.x;
    int base = blockIdx.x * BIN_CHUNK;
    int cnt = e - base;
    if (cnt > BIN_CHUNK) cnt = BIN_CHUNK;
    int is64 = *flag;

    for (int i = t; i < NBK; i += 256) hist[i] = 0;
    __syncthreads();
    if (is64) {
        const long long* pd = (const long long*)ei + e;
        for (int i = t; i < cnt; i += 256) atomicAdd(&hist[((int)pd[base + i]) >> 8], 1);
    } else {
        const int* pd = (const int*)ei + e;
        for (int i = t; i < cnt; i += 256) atomicAdd(&hist[pd[base + i] >> 8], 1);
    }
    __syncthreads();

    // exclusive scan of hist[0..NBK); thread owns slots 2t, 2t+1
    int a0 = hist[2 * t], a1 = hist[2 * t + 1];
    int s = a0 + a1;
    sdata[t] = s;
    __syncthreads();
    for (int off = 1; off < 256; off <<= 1) {
        int val = (t >= off) ? sdata[t - off] : 0;
        __syncthreads();
        sdata[t] += val;
        __syncthreads();
    }
    int excl = sdata[t] - s;
    lstart[2 * t] = excl;
    lstart[2 * t + 1] = excl + a0;
    if (a0 > 0) gbase[2 * t] = atomicAdd(&bc[2 * t], a0);
    if (a1 > 0) gbase[2 * t + 1] = atomicAdd(&bc[2 * t + 1], a1);
    hist[2 * t] = excl;
    hist[2 * t + 1] = excl + a0;
    __syncthreads();

    // place into LDS staging, bucket-sorted
    if (is64) {
        const long long* ps = (const long long*)ei;
        const long long* pd = ps + e;
        for (int i = t; i < cnt; i += 256) {
            int2 p = make_int2((int)ps[base + i], (int)pd[base + i]);
            int pos = atomicAdd(&hist[p.y >> 8], 1);
            stage[pos] = p;
        }
    } else {
        const int* ps = (const int*)ei;
        const int* pd = ps + e;
        for (int i = t; i < cnt; i += 256) {
            int2 p = make_int2(ps[base + i], pd[base + i]);
            int pos = atomicAdd(&hist[p.y >> 8], 1);
            stage[pos] = p;
        }
    }
    __syncthreads();

    // flush: consecutive LDS slots within a bucket -> consecutive global slots
    for (int i = t; i < cnt; i += 256) {
        int2 p = stage[i];
        int b = p.y >> 8;
        staged[gbase[b] + (i - lstart[b])] = p;
    }
}

// one workgroup per bucket: per-node counts/rowptr/dinv + col scatter, all local
__global__ __launch_bounds__(256) void fill_bucket(const int2* __restrict__ staged,
                                                   const int* __restrict__ bbase,
                                                   float* __restrict__ dinv,
                                                   int* __restrict__ rowptr,
                                                   int* __restrict__ col, int n) {
    __shared__ int cnt[DPB];
    __shared__ int scn[DPB];
    int b = blockIdx.x;
    int t = threadIdx.x;
    int dstart = b * DPB;
    int ebeg = bbase[b], eend = bbase[b + 1];
    cnt[t] = 0;
    __syncthreads();
    for (int i = ebeg + t; i < eend; i += 256)
        atomicAdd(&cnt[staged[i].y - dstart], 1);
    __syncthreads();
    int my = cnt[t];
    scn[t] = my;
    __syncthreads();
    for (int off = 1; off < 256; off <<= 1) {
        int val = (t >= off) ? scn[t - off] : 0;
        __syncthreads();
        scn[t] += val;
        __syncthreads();
    }
    int excl = scn[t] - my;
    int v = dstart + t;
    if (v < n) {
        rowptr[v] = ebeg + excl;
        dinv[v] = rsqrtf((float)(my + 1));   // +1: self loop
    }
    cnt[t] = excl;   // reuse as local cursor
    __syncthreads();
    for (int i = ebeg + t; i < eend; i += 256) {
        int2 p = staged[i];
        int pos = atomicAdd(&cnt[p.y - dstart], 1);
        col[ebeg + pos] = p.x;
    }
}

// ---------------- weight packing: fp32 W[128][128] -> bf16 hi/lo B-fragments ----------------

__global__ __launch_bounds__(256) void pack_w(const float* __restrict__ lin0,
                                              const float* __restrict__ conv,
                                              const float* __restrict__ lin1,
                                              uint4* __restrict__ wf) {
    int tid = blockIdx.x * 256 + threadIdx.x;
    if (tid >= 5 * 2048) return;
    int mat = tid >> 11;
    int rem = tid & 2047;
    int ks = rem >> 9;
    int tt = (rem >> 6) & 7;
    int l = rem & 63;
    const float* W = (mat == 0) ? lin0 : (mat == 4) ? lin1 : conv + (size_t)(mat - 1) * 16384;
    int kbase = ks * 32 + (l >> 4) * 8;
    int c = tt * 16 + (l & 15);
    unsigned int hi[4], lo[4];
#pragma unroll
    for (int d = 0; d < 4; ++d) {
        float w0 = W[(kbase + 2 * d) * 128 + c];
        float w1 = W[(kbase + 2 * d + 1) * 128 + c];
        unsigned short h0 = f2bf_rn(w0), h1 = f2bf_rn(w1);
        unsigned short l0 = f2bf_rn(w0 - bf2f(h0)), l1 = f2bf_rn(w1 - bf2f(h1));
        hi[d] = (unsigned int)h0 | ((unsigned int)h1 << 16);
        lo[d] = (unsigned int)l0 | ((unsigned int)l1 << 16);
    }
    int rec = (ks * 8 + tt) * 64 + l;
    wf[(size_t)mat * 4096 + rec] = make_uint4(hi[0], hi[1], hi[2], hi[3]);
    wf[(size_t)mat * 4096 + 2048 + rec] = make_uint4(lo[0], lo[1], lo[2], lo[3]);
}

// ---------------- MFMA GEMM: C[M,128] = A[M,128] @ W[128,128] ----------------
// AFP16: A is fp16 row-major (exactly split into bf16 hi/lo); else fp32.
// mode 0: relu(A@W + bias) -> fp16 h row-major
// mode 1: dinv[row]*(A@W) -> fp16 chunk-major [8][M][16]
// mode 2: A@W + bias -> fp32 out

template <int AFP16>
__global__ __launch_bounds__(512) void gemm_mfma(
    const void* __restrict__ A, const uint4* __restrict__ wf,
    const float* __restrict__ bias, const float* __restrict__ dinv,
    void* __restrict__ Cout, int M, int mode) {
    __shared__ uint4 WfL[4096];   // 64 KB: [part*2048 + rec]

    int t = threadIdx.x;
#pragma unroll
    for (int i = 0; i < 8; ++i) WfL[t + i * 512] = wf[t + i * 512];

    int wave = t >> 6, lane = t & 63;
    int lrow = lane & 15, lgrp = lane >> 4;
    int r0 = blockIdx.x * 128 + wave * 16;

    f32x4 acc[8];
#pragma unroll
    for (int i = 0; i < 8; ++i) acc[i] = (f32x4){0.f, 0.f, 0.f, 0.f};

    __syncthreads();

    int arow = r0 + lrow;
    if (arow >= M) arow = M - 1;          // clamp (stores are guarded)
    const char* ap = (const char*)A +
        (AFP16 ? ((size_t)arow * 256 + lgrp * 16) : ((size_t)arow * 512 + lgrp * 32));

#pragma unroll
    for (int ks = 0; ks < 4; ++ks) {
        float av[8];
        if (AFP16) {
            uint4 q = *(const uint4*)(ap + ks * 64);
            unsigned int w[4] = {q.x, q.y, q.z, q.w};
#pragma unroll
            for (int d = 0; d < 4; ++d) {
                __half2 h2 = *(__half2*)&w[d];
                float2 f2 = __half22float2(h2);
                av[2 * d] = f2.x;
                av[2 * d + 1] = f2.y;
            }
        } else {
            float4 v0 = *(const float4*)(ap + ks * 128);
            float4 v1 = *(const float4*)(ap + ks * 128 + 16);
            av[0] = v0.x; av[1] = v0.y; av[2] = v0.z; av[3] = v0.w;
            av[4] = v1.x; av[5] = v1.y; av[6] = v1.z; av[7] = v1.w;
        }
        bf16x8 ahi, alo;
#pragma unroll
        for (int j = 0; j < 8; ++j) {
            unsigned short h = f2bf_rn(av[j]);
            ahi[j] = (short)h;
            alo[j] = (short)f2bf_rn(av[j] - bf2f(h));
        }
#pragma unroll
        for (int tt = 0; tt < 8; ++tt) {
            bf16x8 bhi = *(const bf16x8*)&WfL[(ks * 8 + tt) * 64 + lane];
            bf16x8 blo = *(const bf16x8*)&WfL[2048 + (ks * 8 + tt) * 64 + lane];
            acc[tt] = __builtin_amdgcn_mfma_f32_16x16x32_bf16(ahi, bhi, acc[tt], 0, 0, 0);
            acc[tt] = __builtin_amdgcn_mfma_f32_16x16x32_bf16(ahi, blo, acc[tt], 0, 0, 0);
            acc[tt] = __builtin_amdgcn_mfma_f32_16x16x32_bf16(alo, bhi, acc[tt], 0, 0, 0);
        }
    }

    // epilogue: D row = r0 + lgrp*4 + j, col = tt*16 + lrow
    int rbase = r0 + lgrp * 4;
    float dv[4] = {0.f, 0.f, 0.f, 0.f};
    if (mode == 1) {
#pragma unroll
        for (int j = 0; j < 4; ++j) dv[j] = (rbase + j < M) ? dinv[rbase + j] : 0.f;
    }
#pragma unroll
    for (int tt = 0; tt < 8; ++tt) {
        int c = tt * 16 + lrow;
        float bc_ = (mode != 1) ? bias[c] : 0.f;
        int ch = c >> 4, cin = c & 15;
#pragma unroll
        for (int j = 0; j < 4; ++j) {
            int r = rbase + j;
            if (r >= M) continue;
            float val = acc[tt][j];
            if (mode == 0) {
                ((__half*)Cout)[(size_t)r * 128 + c] = __float2half(fmaxf(val + bc_, 0.f));
            } else if (mode == 1) {
                ((__half*)Cout)[(size_t)ch * M * 16 + (size_t)r * 16 + cin] =
                    __float2half(val * dv[j]);
            } else {
                ((float*)Cout)[(size_t)r * 128 + c] = val + bc_;
            }
        }
    }
}

// ---------------- XCD-pinned chunked aggregation + bias + BN + ReLU ----------------
// 8 chunks of 16 channels; chunk = blockIdx.x & 7 pins chunk c to XCD c
// (round-robin block->XCD). Per-XCD gather slice = N*16ch*2B = 3.2MB (L2-resident).
// 8-lane group per node (32 nodes/block); each gather = 8 lanes x half2 = 32B row.

__global__ __launch_bounds__(256) void agg_bn_relu_c(
    const __half2* __restrict__ hwc, const int* __restrict__ rowptr,
    const int* __restrict__ col, const float* __restrict__ dinv,
    const float* __restrict__ convb, const float* __restrict__ gamma,
    const float* __restrict__ beta, const float* __restrict__ mean,
    const float* __restrict__ var, __half2* __restrict__ hout, int n) {
    int g = blockIdx.x;
    int chunk = g & 7;
    int nodeblk = g >> 3;
    int t = threadIdx.x;
    int l8 = t & 7;
    int v = nodeblk * 32 + (t >> 3);
    if (v >= n) return;

    const __half2* base = hwc + (size_t)chunk * n * 8;
    float2 acc = __half22float2(base[(size_t)v * 8 + l8]);   // self-loop term

    int gb = t & 56;   // wave-local 8-lane group base
    int beg = rowptr[v], end = rowptr[v + 1];
    for (int p = beg; p < end; p += 8) {
        int cnt = end - p;
        if (cnt > 8) cnt = 8;
        int myc = (l8 < cnt) ? col[p + l8] : 0;
        int j = 0;
        for (; j + 4 <= cnt; j += 4) {
            int u0 = __shfl(myc, gb + j);
            int u1 = __shfl(myc, gb + j + 1);
            int u2 = __shfl(myc, gb + j + 2);
            int u3 = __shfl(myc, gb + j + 3);
            float2 m0 = __half22float2(base[(size_t)u0 * 8 + l8]);
            float2 m1 = __half22float2(base[(size_t)u1 * 8 + l8]);
            float2 m2 = __half22float2(base[(size_t)u2 * 8 + l8]);
            float2 m3 = __half22float2(base[(size_t)u3 * 8 + l8]);
            acc.x += (m0.x + m1.x) + (m2.x + m3.x);
            acc.y += (m0.y + m1.y) + (m2.y + m3.y);
        }
        for (; j < cnt; ++j) {
            int u = __shfl(myc, gb + j);
            float2 m = __half22float2(base[(size_t)u * 8 + l8]);
            acc.x += m.x;
            acc.y += m.y;
        }
    }

    float dvv = dinv[v];
    int c0 = chunk * 16 + 2 * l8;
    float2 g2 = *(const float2*)(gamma + c0);
    float2 be = *(const float2*)(beta + c0);
    float2 mn = *(const float2*)(mean + c0);
    float2 va = *(const float2*)(var + c0);
    float2 cb = *(const float2*)(convb + c0);
    float s0 = g2.x * rsqrtf(va.x + BN_EPS);
    float s1 = g2.y * rsqrtf(va.y + BN_EPS);
    float o0 = (dvv * acc.x + cb.x - mn.x) * s0 + be.x;
    float o1 = (dvv * acc.y + cb.y - mn.y) * s1 + be.y;
    o0 = fmaxf(o0, 0.0f);
    o1 = fmaxf(o1, 0.0f);
    hout[(size_t)v * 64 + chunk * 8 + l8] = __floats2half2_rn(o0, o1);
}

// ---------------- launch ----------------

extern "C" void kernel_launch(void* const* d_in, const int* in_sizes, int n_in,
                              void* d_out, int out_size, void* d_ws, size_t ws_size,
                              hipStream_t stream) {
    const float* x      = (const float*)d_in[0];
    const void*  ei     = d_in[1];
    const float* lin0_w = (const float*)d_in[3];
    const float* lin0_b = (const float*)d_in[4];
    const float* lin1_w = (const float*)d_in[5];
    const float* lin1_b = (const float*)d_in[6];
    const float* conv_w = (const float*)d_in[7];
    const float* conv_b = (const float*)d_in[8];
    const float* bn_g   = (const float*)d_in[9];
    const float* bn_b   = (const float*)d_in[10];
    const float* bn_m   = (const float*)d_in[11];
    const float* bn_v   = (const float*)d_in[12];

    int n = in_sizes[0] / HIDC;   // 100000
    int e = in_sizes[1] / 2;      // 1600000
    int nbk = (n + DPB - 1) / DPB;   // 391

    char* ws = (char*)d_ws;
    size_t off = 0;
    auto alloc = [&](size_t bytes) -> void* {
        void* p = ws + off;
        off += (bytes + 255) & ~(size_t)255;
        return p;
    };
    __half2* h16    = (__half2*)alloc((size_t)n * HIDC * 2);
    __half2* hwc    = (__half2*)alloc((size_t)n * HIDC * 2);
    int2*    staged = (int2*)alloc((size_t)e * 8);
    int*     col    = (int*)alloc((size_t)e * 4);
    float*   dinv   = (float*)alloc((size_t)n * 4);
    int*     rowptr = (int*)alloc(((size_t)n + 1) * 4);
    int*     bkt    = (int*)alloc((size_t)NBK * 4);
    int*     bbase  = (int*)alloc((size_t)(NBK + 1) * 4);
    int*     bc     = (int*)alloc((size_t)NBK * 4);
    uint4*   wf     = (uint4*)alloc((size_t)5 * 4096 * 16);
    int*     flag   = (int*)alloc(256);

    hipMemsetAsync(bkt, 0, (size_t)NBK * 4, stream);

    detect64<<<1, 64, 0, stream>>>((const unsigned int*)ei, flag);
    pack_w<<<40, 256, 0, stream>>>(lin0_w, conv_w, lin1_w, wf);

    int binb = (e + BIN_CHUNK - 1) / BIN_CHUNK;
    bucket_count<<<binb, 256, 0, stream>>>(ei, flag, bkt, e);
    scan_buckets<<<1, 512, 0, stream>>>(bkt, bbase, bc, rowptr, n, e, nbk);
    bin_pairs<<<binb, 256, 0, stream>>>(ei, flag, bc, staged, e);
    fill_bucket<<<nbk, 256, 0, stream>>>(staged, bbase, dinv, rowptr, col, n);

    int gb = (n + 127) / 128;
    // h = relu(x @ W0 + b0)   (fp32 A -> fp16 h)
    gemm_mfma<0><<<gb, 512, 0, stream>>>(x, wf, lin0_b, nullptr, h16, n, 0);

    int nbpc = (n + 31) / 32;            // node-blocks per chunk
    int ag = 8 * nbpc;                   // chunk = blockIdx & 7 (XCD-pinned)
    for (int l = 0; l < 3; ++l) {
        // hwc = dinv * (h @ Wl)   (fp16 chunk-major [8][N][16])
        gemm_mfma<1><<<gb, 512, 0, stream>>>(h16, wf + (size_t)(1 + l) * 4096, nullptr, dinv, hwc, n, 1);
        agg_bn_relu_c<<<ag, 256, 0, stream>>>(hwc, rowptr, col, dinv,
                                              conv_b + (size_t)l * HIDC,
                                              bn_g + (size_t)l * HIDC, bn_b + (size_t)l * HIDC,
                                              bn_m + (size_t)l * HIDC, bn_v + (size_t)l * HIDC,
                                              h16, n);
    }
    // out = h @ W4 + b4  (fp32 out)
    gemm_mfma<1><<<gb, 512, 0, stream>>>(h16, wf + (size_t)4 * 4096, lin1_b, nullptr, d_out, n, 2);
}

// Round 6
// 382.652 us; speedup vs baseline: 1.2269x; 1.2269x over previous
//
#include <hip/hip_runtime.h>
#include <hip/hip_fp16.h>

// LinkPredictorBackbone: GCN backbone, N=100000 nodes, E=1600000 edges, C=128.
// Round 6 pipeline:
//   graph build: bucket-count (LDS hist) -> bucket scan -> bin (bucket-major)
//                -> fill_bucket (per-node count/rowptr/dinv/col all in-LDS)
//   weights: pack all 5 128x128 fp32 W into bf16 hi/lo MFMA B-fragment records
//   gemm_mfma<AFP16>: split-bf16 MFMA; A fp32 (layer 0) or fp16 (h);
//     mode 0 -> h fp16 row-major; mode 1 -> hw fp16 row-major (dinv-scaled);
//     mode 2 -> fp32 d_out
//   agg_bn_relu: wave-per-node full-row gather (256B/edge), 8-deep unrolled
//     independent loads for miss-level parallelism; BN+ReLU fused; h fp16 out.

#define HIDC 128
#define BN_EPS 1e-5f
#define DPB 256          // dsts per bucket
#define NBK 512          // bucket array size (>= ceil(N/DPB))
#define BIN_CHUNK 8192   // edges per binning block

typedef short bf16x8 __attribute__((ext_vector_type(8)));
typedef float f32x4 __attribute__((ext_vector_type(4)));

__device__ __forceinline__ unsigned short f2bf_rn(float x) {
    unsigned int u = __float_as_uint(x);
    unsigned int r = u + 0x7fffu + ((u >> 16) & 1u);
    return (unsigned short)(r >> 16);
}
__device__ __forceinline__ float bf2f(unsigned short b) {
    return __uint_as_float(((unsigned int)b) << 16);
}

// ---------------- graph build ----------------

__global__ void detect64(const unsigned int* ei, int* flag) {
    if (threadIdx.x != 0 || blockIdx.x != 0) return;
    int is64 = 1;
    for (int i = 0; i < 64; ++i) {
        if (ei[2 * i + 1] != 0u) { is64 = 0; break; }
    }
    *flag = is64;
}

__global__ __launch_bounds__(256) void bucket_count(const void* __restrict__ ei,
                                                    const int* __restrict__ flag,
                                                    int* __restrict__ bkt, int e) {
    __shared__ int h[NBK];
    int t = threadIdx.x;
    for (int i = t; i < NBK; i += 256) h[i] = 0;
    __syncthreads();
    int base = blockIdx.x * BIN_CHUNK;
    int cnt = e - base;
    if (cnt > BIN_CHUNK) cnt = BIN_CHUNK;
    if (*flag) {
        const long long* pd = (const long long*)ei + e;
        for (int i = t; i < cnt; i += 256) atomicAdd(&h[((int)pd[base + i]) >> 8], 1);
    } else {
        const int* pd = (const int*)ei + e;
        for (int i = t; i < cnt; i += 256) atomicAdd(&h[pd[base + i] >> 8], 1);
    }
    __syncthreads();
    for (int i = t; i < NBK; i += 256) if (h[i]) atomicAdd(&bkt[i], h[i]);
}

// single block of 512: exclusive scan of bucket counts -> bbase (cursor copy bc)
__global__ void scan_buckets(const int* __restrict__ bkt, int* __restrict__ bbase,
                             int* __restrict__ bc, int* __restrict__ rowptr,
                             int n, int e, int nbk) {
    __shared__ int s[NBK];
    int t = threadIdx.x;
    int v = (t < nbk) ? bkt[t] : 0;
    s[t] = v;
    __syncthreads();
    for (int off = 1; off < NBK; off <<= 1) {
        int val = (t >= off) ? s[t - off] : 0;
        __syncthreads();
        s[t] += val;
        __syncthreads();
    }
    int excl = s[t] - v;     // exclusive prefix (== e for t >= nbk)
    bbase[t] = excl;
    bc[t] = excl;
    if (t == 0) rowptr[n] = e;
}

// bin edges into bucket-major order with coalesced flushes via LDS staging
__global__ __launch_bounds__(256) void bin_pairs(const void* __restrict__ ei,
                                                 const int* __restrict__ flag,
                                                 int* __restrict__ bc,
                                                 int2* __restrict__ staged, int e) {
    __shared__ int hist[NBK];      // later reused as local placement cursor
    __shared__ int lstart[NBK];
    __shared__ int gbase[NBK];
    __shared__ int sdata[256];
    __shared__ int2 stage[BIN_CHUNK];   // 64 KB

    int t = threadIdx.x;
    int base = blockIdx.x * BIN_CHUNK;
    int cnt = e - base;
    if (cnt > BIN_CHUNK) cnt = BIN_CHUNK;
    int is64 = *flag;

    for (int i = t; i < NBK; i += 256) hist[i] = 0;
    __syncthreads();
    if (is64) {
        const long long* pd = (const long long*)ei + e;
        for (int i = t; i < cnt; i += 256) atomicAdd(&hist[((int)pd[base + i]) >> 8], 1);
    } else {
        const int* pd = (const int*)ei + e;
        for (int i = t; i < cnt; i += 256) atomicAdd(&hist[pd[base + i] >> 8], 1);
    }
    __syncthreads();

    // exclusive scan of hist[0..NBK); thread owns slots 2t, 2t+1
    int a0 = hist[2 * t], a1 = hist[2 * t + 1];
    int s = a0 + a1;
    sdata[t] = s;
    __syncthreads();
    for (int off = 1; off < 256; off <<= 1) {
        int val = (t >= off) ? sdata[t - off] : 0;
        __syncthreads();
        sdata[t] += val;
        __syncthreads();
    }
    int excl = sdata[t] - s;
    lstart[2 * t] = excl;
    lstart[2 * t + 1] = excl + a0;
    if (a0 > 0) gbase[2 * t] = atomicAdd(&bc[2 * t], a0);
    if (a1 > 0) gbase[2 * t + 1] = atomicAdd(&bc[2 * t + 1], a1);
    hist[2 * t] = excl;
    hist[2 * t + 1] = excl + a0;
    __syncthreads();

    // place into LDS staging, bucket-sorted
    if (is64) {
        const long long* ps = (const long long*)ei;
        const long long* pd = ps + e;
        for (int i = t; i < cnt; i += 256) {
            int2 p = make_int2((int)ps[base + i], (int)pd[base + i]);
            int pos = atomicAdd(&hist[p.y >> 8], 1);
            stage[pos] = p;
        }
    } else {
        const int* ps = (const int*)ei;
        const int* pd = ps + e;
        for (int i = t; i < cnt; i += 256) {
            int2 p = make_int2(ps[base + i], pd[base + i]);
            int pos = atomicAdd(&hist[p.y >> 8], 1);
            stage[pos] = p;
        }
    }
    __syncthreads();

    // flush: consecutive LDS slots within a bucket -> consecutive global slots
    for (int i = t; i < cnt; i += 256) {
        int2 p = stage[i];
        int b = p.y >> 8;
        staged[gbase[b] + (i - lstart[b])] = p;
    }
}

// one workgroup per bucket: per-node counts/rowptr/dinv + col scatter, all local
__global__ __launch_bounds__(256) void fill_bucket(const int2* __restrict__ staged,
                                                   const int* __restrict__ bbase,
                                                   float* __restrict__ dinv,
                                                   int* __restrict__ rowptr,
                                                   int* __restrict__ col, int n) {
    __shared__ int cnt[DPB];
    __shared__ int scn[DPB];
    int b = blockIdx.x;
    int t = threadIdx.x;
    int dstart = b * DPB;
    int ebeg = bbase[b], eend = bbase[b + 1];
    cnt[t] = 0;
    __syncthreads();
    for (int i = ebeg + t; i < eend; i += 256)
        atomicAdd(&cnt[staged[i].y - dstart], 1);
    __syncthreads();
    int my = cnt[t];
    scn[t] = my;
    __syncthreads();
    for (int off = 1; off < 256; off <<= 1) {
        int val = (t >= off) ? scn[t - off] : 0;
        __syncthreads();
        scn[t] += val;
        __syncthreads();
    }
    int excl = scn[t] - my;
    int v = dstart + t;
    if (v < n) {
        rowptr[v] = ebeg + excl;
        dinv[v] = rsqrtf((float)(my + 1));   // +1: self loop
    }
    cnt[t] = excl;   // reuse as local cursor
    __syncthreads();
    for (int i = ebeg + t; i < eend; i += 256) {
        int2 p = staged[i];
        int pos = atomicAdd(&cnt[p.y - dstart], 1);
        col[ebeg + pos] = p.x;
    }
}

// ---------------- weight packing: fp32 W[128][128] -> bf16 hi/lo B-fragments ----------------

__global__ __launch_bounds__(256) void pack_w(const float* __restrict__ lin0,
                                              const float* __restrict__ conv,
                                              const float* __restrict__ lin1,
                                              uint4* __restrict__ wf) {
    int tid = blockIdx.x * 256 + threadIdx.x;
    if (tid >= 5 * 2048) return;
    int mat = tid >> 11;
    int rem = tid & 2047;
    int ks = rem >> 9;
    int tt = (rem >> 6) & 7;
    int l = rem & 63;
    const float* W = (mat == 0) ? lin0 : (mat == 4) ? lin1 : conv + (size_t)(mat - 1) * 16384;
    int kbase = ks * 32 + (l >> 4) * 8;
    int c = tt * 16 + (l & 15);
    unsigned int hi[4], lo[4];
#pragma unroll
    for (int d = 0; d < 4; ++d) {
        float w0 = W[(kbase + 2 * d) * 128 + c];
        float w1 = W[(kbase + 2 * d + 1) * 128 + c];
        unsigned short h0 = f2bf_rn(w0), h1 = f2bf_rn(w1);
        unsigned short l0 = f2bf_rn(w0 - bf2f(h0)), l1 = f2bf_rn(w1 - bf2f(h1));
        hi[d] = (unsigned int)h0 | ((unsigned int)h1 << 16);
        lo[d] = (unsigned int)l0 | ((unsigned int)l1 << 16);
    }
    int rec = (ks * 8 + tt) * 64 + l;
    wf[(size_t)mat * 4096 + rec] = make_uint4(hi[0], hi[1], hi[2], hi[3]);
    wf[(size_t)mat * 4096 + 2048 + rec] = make_uint4(lo[0], lo[1], lo[2], lo[3]);
}

// ---------------- MFMA GEMM: C[M,128] = A[M,128] @ W[128,128] ----------------
// AFP16: A is fp16 row-major (exactly split into bf16 hi/lo); else fp32.
// mode 0: relu(A@W + bias) -> fp16 row-major
// mode 1: dinv[row]*(A@W) -> fp16 row-major
// mode 2: A@W + bias -> fp32 out

template <int AFP16>
__global__ __launch_bounds__(512) void gemm_mfma(
    const void* __restrict__ A, const uint4* __restrict__ wf,
    const float* __restrict__ bias, const float* __restrict__ dinv,
    void* __restrict__ Cout, int M, int mode) {
    __shared__ uint4 WfL[4096];   // 64 KB: [part*2048 + rec]

    int t = threadIdx.x;
#pragma unroll
    for (int i = 0; i < 8; ++i) WfL[t + i * 512] = wf[t + i * 512];

    int wave = t >> 6, lane = t & 63;
    int lrow = lane & 15, lgrp = lane >> 4;
    int r0 = blockIdx.x * 128 + wave * 16;

    f32x4 acc[8];
#pragma unroll
    for (int i = 0; i < 8; ++i) acc[i] = (f32x4){0.f, 0.f, 0.f, 0.f};

    __syncthreads();

    int arow = r0 + lrow;
    if (arow >= M) arow = M - 1;          // clamp (stores are guarded)
    const char* ap = (const char*)A +
        (AFP16 ? ((size_t)arow * 256 + lgrp * 16) : ((size_t)arow * 512 + lgrp * 32));

#pragma unroll
    for (int ks = 0; ks < 4; ++ks) {
        float av[8];
        if (AFP16) {
            uint4 q = *(const uint4*)(ap + ks * 64);
            unsigned int w[4] = {q.x, q.y, q.z, q.w};
#pragma unroll
            for (int d = 0; d < 4; ++d) {
                __half2 h2 = *(__half2*)&w[d];
                float2 f2 = __half22float2(h2);
                av[2 * d] = f2.x;
                av[2 * d + 1] = f2.y;
            }
        } else {
            float4 v0 = *(const float4*)(ap + ks * 128);
            float4 v1 = *(const float4*)(ap + ks * 128 + 16);
            av[0] = v0.x; av[1] = v0.y; av[2] = v0.z; av[3] = v0.w;
            av[4] = v1.x; av[5] = v1.y; av[6] = v1.z; av[7] = v1.w;
        }
        bf16x8 ahi, alo;
#pragma unroll
        for (int j = 0; j < 8; ++j) {
            unsigned short h = f2bf_rn(av[j]);
            ahi[j] = (short)h;
            alo[j] = (short)f2bf_rn(av[j] - bf2f(h));
        }
#pragma unroll
        for (int tt = 0; tt < 8; ++tt) {
            bf16x8 bhi = *(const bf16x8*)&WfL[(ks * 8 + tt) * 64 + lane];
            bf16x8 blo = *(const bf16x8*)&WfL[2048 + (ks * 8 + tt) * 64 + lane];
            acc[tt] = __builtin_amdgcn_mfma_f32_16x16x32_bf16(ahi, bhi, acc[tt], 0, 0, 0);
            acc[tt] = __builtin_amdgcn_mfma_f32_16x16x32_bf16(ahi, blo, acc[tt], 0, 0, 0);
            acc[tt] = __builtin_amdgcn_mfma_f32_16x16x32_bf16(alo, bhi, acc[tt], 0, 0, 0);
        }
    }

    // epilogue: D row = r0 + lgrp*4 + j, col = tt*16 + lrow
    int rbase = r0 + lgrp * 4;
    float dv[4] = {0.f, 0.f, 0.f, 0.f};
    if (mode == 1) {
#pragma unroll
        for (int j = 0; j < 4; ++j) dv[j] = (rbase + j < M) ? dinv[rbase + j] : 0.f;
    }
#pragma unroll
    for (int tt = 0; tt < 8; ++tt) {
        int c = tt * 16 + lrow;
        float bc_ = (mode != 1) ? bias[c] : 0.f;
#pragma unroll
        for (int j = 0; j < 4; ++j) {
            int r = rbase + j;
            if (r >= M) continue;
            float val = acc[tt][j];
            if (mode == 0) {
                ((__half*)Cout)[(size_t)r * 128 + c] = __float2half(fmaxf(val + bc_, 0.f));
            } else if (mode == 1) {
                ((__half*)Cout)[(size_t)r * 128 + c] = __float2half(val * dv[j]);
            } else {
                ((float*)Cout)[(size_t)r * 128 + c] = val + bc_;
            }
        }
    }
}

// ---------------- aggregation + bias + BN + ReLU ----------------
// wave per node; lane handles channels 2*lane, 2*lane+1 (half2 -> 256B full-row
// gather per edge); 8-deep independent-load unroll for miss-level parallelism.

__global__ __launch_bounds__(256) void agg_bn_relu(
    const __half2* __restrict__ hw, const int* __restrict__ rowptr,
    const int* __restrict__ col, const float* __restrict__ dinv,
    const float* __restrict__ convb, const float* __restrict__ gamma,
    const float* __restrict__ beta, const float* __restrict__ mean,
    const float* __restrict__ var, __half2* __restrict__ hout, int n) {
    int lane = threadIdx.x & 63;
    int v = (blockIdx.x * 256 + threadIdx.x) >> 6;
    if (v >= n) return;

    float2 acc = __half22float2(hw[(size_t)v * 64 + lane]);   // self-loop term

    int beg = rowptr[v], end = rowptr[v + 1];
    for (int p = beg; p < end; p += 64) {
        int cnt = end - p;
        if (cnt > 64) cnt = 64;
        int myc = (lane < cnt) ? col[p + lane] : 0;
        int j = 0;
        for (; j + 8 <= cnt; j += 8) {
            int u0 = __shfl(myc, j);
            int u1 = __shfl(myc, j + 1);
            int u2 = __shfl(myc, j + 2);
            int u3 = __shfl(myc, j + 3);
            int u4 = __shfl(myc, j + 4);
            int u5 = __shfl(myc, j + 5);
            int u6 = __shfl(myc, j + 6);
            int u7 = __shfl(myc, j + 7);
            float2 m0 = __half22float2(hw[(size_t)u0 * 64 + lane]);
            float2 m1 = __half22float2(hw[(size_t)u1 * 64 + lane]);
            float2 m2 = __half22float2(hw[(size_t)u2 * 64 + lane]);
            float2 m3 = __half22float2(hw[(size_t)u3 * 64 + lane]);
            float2 m4 = __half22float2(hw[(size_t)u4 * 64 + lane]);
            float2 m5 = __half22float2(hw[(size_t)u5 * 64 + lane]);
            float2 m6 = __half22float2(hw[(size_t)u6 * 64 + lane]);
            float2 m7 = __half22float2(hw[(size_t)u7 * 64 + lane]);
            acc.x += ((m0.x + m1.x) + (m2.x + m3.x)) + ((m4.x + m5.x) + (m6.x + m7.x));
            acc.y += ((m0.y + m1.y) + (m2.y + m3.y)) + ((m4.y + m5.y) + (m6.y + m7.y));
        }
        for (; j < cnt; ++j) {
            int u = __shfl(myc, j);
            float2 m = __half22float2(hw[(size_t)u * 64 + lane]);
            acc.x += m.x;
            acc.y += m.y;
        }
    }

    float dvv = dinv[v];
    int c0 = lane * 2;
    float2 g  = *(const float2*)(gamma + c0);
    float2 be = *(const float2*)(beta + c0);
    float2 mn = *(const float2*)(mean + c0);
    float2 va = *(const float2*)(var + c0);
    float2 cb = *(const float2*)(convb + c0);
    float s0 = g.x * rsqrtf(va.x + BN_EPS);
    float s1 = g.y * rsqrtf(va.y + BN_EPS);
    float o0 = (dvv * acc.x + cb.x - mn.x) * s0 + be.x;
    float o1 = (dvv * acc.y + cb.y - mn.y) * s1 + be.y;
    o0 = fmaxf(o0, 0.0f);
    o1 = fmaxf(o1, 0.0f);
    hout[(size_t)v * 64 + lane] = __floats2half2_rn(o0, o1);
}

// ---------------- launch ----------------

extern "C" void kernel_launch(void* const* d_in, const int* in_sizes, int n_in,
                              void* d_out, int out_size, void* d_ws, size_t ws_size,
                              hipStream_t stream) {
    const float* x      = (const float*)d_in[0];
    const void*  ei     = d_in[1];
    const float* lin0_w = (const float*)d_in[3];
    const float* lin0_b = (const float*)d_in[4];
    const float* lin1_w = (const float*)d_in[5];
    const float* lin1_b = (const float*)d_in[6];
    const float* conv_w = (const float*)d_in[7];
    const float* conv_b = (const float*)d_in[8];
    const float* bn_g   = (const float*)d_in[9];
    const float* bn_b   = (const float*)d_in[10];
    const float* bn_m   = (const float*)d_in[11];
    const float* bn_v   = (const float*)d_in[12];

    int n = in_sizes[0] / HIDC;   // 100000
    int e = in_sizes[1] / 2;      // 1600000
    int nbk = (n + DPB - 1) / DPB;   // 391

    char* ws = (char*)d_ws;
    size_t off = 0;
    auto alloc = [&](size_t bytes) -> void* {
        void* p = ws + off;
        off += (bytes + 255) & ~(size_t)255;
        return p;
    };
    __half2* h16    = (__half2*)alloc((size_t)n * HIDC * 2);
    __half2* hw     = (__half2*)alloc((size_t)n * HIDC * 2);
    int2*    staged = (int2*)alloc((size_t)e * 8);
    int*     col    = (int*)alloc((size_t)e * 4);
    float*   dinv   = (float*)alloc((size_t)n * 4);
    int*     rowptr = (int*)alloc(((size_t)n + 1) * 4);
    int*     bkt    = (int*)alloc((size_t)NBK * 4);
    int*     bbase  = (int*)alloc((size_t)(NBK + 1) * 4);
    int*     bc     = (int*)alloc((size_t)NBK * 4);
    uint4*   wf     = (uint4*)alloc((size_t)5 * 4096 * 16);
    int*     flag   = (int*)alloc(256);

    hipMemsetAsync(bkt, 0, (size_t)NBK * 4, stream);

    detect64<<<1, 64, 0, stream>>>((const unsigned int*)ei, flag);
    pack_w<<<40, 256, 0, stream>>>(lin0_w, conv_w, lin1_w, wf);

    int binb = (e + BIN_CHUNK - 1) / BIN_CHUNK;
    bucket_count<<<binb, 256, 0, stream>>>(ei, flag, bkt, e);
    scan_buckets<<<1, 512, 0, stream>>>(bkt, bbase, bc, rowptr, n, e, nbk);
    bin_pairs<<<binb, 256, 0, stream>>>(ei, flag, bc, staged, e);
    fill_bucket<<<nbk, 256, 0, stream>>>(staged, bbase, dinv, rowptr, col, n);

    int gb = (n + 127) / 128;
    // h = relu(x @ W0 + b0)   (fp32 A -> fp16 h)
    gemm_mfma<0><<<gb, 512, 0, stream>>>(x, wf, lin0_b, nullptr, h16, n, 0);

    int ab = (n + 3) / 4;
    for (int l = 0; l < 3; ++l) {
        // hw = dinv * (h @ Wl)   (fp16 row-major)
        gemm_mfma<1><<<gb, 512, 0, stream>>>(h16, wf + (size_t)(1 + l) * 4096, nullptr, dinv, hw, n, 1);
        agg_bn_relu<<<ab, 256, 0, stream>>>(hw, rowptr, col, dinv,
                                            conv_b + (size_t)l * HIDC,
                                            bn_g + (size_t)l * HIDC, bn_b + (size_t)l * HIDC,
                                            bn_m + (size_t)l * HIDC, bn_v + (size_t)l * HIDC,
                                            h16, n);
    }
    // out = h @ W4 + b4  (fp32 out)
    gemm_mfma<1><<<gb, 512, 0, stream>>>(h16, wf + (size_t)4 * 4096, lin1_b, nullptr, d_out, n, 2);
}